// Round 1
// baseline (316.099 us; speedup 1.0000x reference)
//
#include <hip/hip_runtime.h>
#include <cstdint>

#define DEVINL __device__ __forceinline__

using bfrag = __attribute__((ext_vector_type(8))) __bf16;     // MFMA A/B operand (4 VGPRs)
using f32x4 = __attribute__((ext_vector_type(4))) float;      // MFMA C/D
using u16x2 = __attribute__((ext_vector_type(2))) unsigned short;
using u16x4 = __attribute__((ext_vector_type(4))) unsigned short;
using u16x8 = __attribute__((ext_vector_type(8))) unsigned short;

// Problem constants (B=2, S=2048, D=1024, H=16, DK=64)
static constexpr int S_ = 2048;
static constexpr int D_ = 1024;
static constexpr int MROWS = 4096;  // B*S

DEVINL unsigned short f2bf(float f) {  // round-to-nearest-even f32 -> bf16
  union { float f; unsigned int u; } v; v.f = f;
  unsigned int r = v.u + 0x7fffu + ((v.u >> 16) & 1u);
  return (unsigned short)(r >> 16);
}

DEVINL void async_copy16(void* lds, const void* g) {
  // HW adds lane*16 to the (wave-uniform) LDS base
  __builtin_amdgcn_global_load_lds(
      (const __attribute__((address_space(1))) unsigned int*)g,
      (__attribute__((address_space(3))) unsigned int*)lds, 16, 0, 0);
}

// ---------------- fp32 -> bf16 convert (vectorized) ----------------
__global__ __launch_bounds__(256) void cvt_bf16(const float* __restrict__ in,
                                                unsigned short* __restrict__ out, int n4) {
  int i = blockIdx.x * 256 + threadIdx.x;
  if (i >= n4) return;
  f32x4 v = ((const f32x4*)in)[i];
  u16x4 o;
  o[0] = f2bf(v[0]); o[1] = f2bf(v[1]); o[2] = f2bf(v[2]); o[3] = f2bf(v[3]);
  ((u16x4*)out)[i] = o;
}

// ---------------- mask [B,1,S,S] int32 -> bitmask (64 kv per u64 word) ----------------
__global__ __launch_bounds__(256) void pack_mask(const int* __restrict__ mask,
                                                 unsigned long long* __restrict__ bits) {
  size_t i = (size_t)blockIdx.x * 256 + threadIdx.x;
  unsigned long long b = __ballot(mask[i] != 0);
  if ((threadIdx.x & 63) == 0) bits[i >> 6] = b;
}

// ---------------- GEMM: C[m,n] = bias[n] + sum_k A[m,k] * W[n,k]  (x @ W.T + b) ----------------
// 128x128 tile, BK=64, 256 threads (4 waves, each owns a 64x64 quadrant), 16x16x32 bf16 MFMA.
template <bool OUTF32>
__global__ __launch_bounds__(256, 2) void gemm_bt(const unsigned short* __restrict__ A,
                                                  const unsigned short* __restrict__ W,
                                                  const float* __restrict__ bias,
                                                  void* __restrict__ Cout,
                                                  int M, int N, int K) {
  __shared__ unsigned short As[128 * 64];
  __shared__ unsigned short Bs[128 * 64];
  const int t = threadIdx.x;
  const int lane = t & 63, wave = t >> 6;
  const int wr = wave >> 1, wc = wave & 1;      // wave quadrant (2x2 of 64x64)
  const int g = lane >> 4, q = lane & 15;       // fragment coords
  const int m0 = blockIdx.y * 128, n0 = blockIdx.x * 128;

  f32x4 acc[4][4] = {};                          // [mi][nj]

  const int srow = t >> 3;                       // staging: 32 rows per chunk
  const int scol = (t & 7) * 8;                  // 8 bf16 = 16B per lane
  const size_t abase = (size_t)(m0 + srow) * K + scol;
  const size_t bbase = (size_t)(n0 + srow) * K + scol;
  char* AsB = (char*)As;
  char* BsB = (char*)Bs;

  for (int k0 = 0; k0 < K; k0 += 64) {
    __syncthreads();  // previous compute done before overwriting LDS
#pragma unroll
    for (int c = 0; c < 4; ++c) {
      async_copy16(AsB + c * 4096 + wave * 1024, A + abase + (size_t)c * 32 * K + k0);
      async_copy16(BsB + c * 4096 + wave * 1024, W + bbase + (size_t)c * 32 * K + k0);
    }
    __syncthreads();  // compiler drains vmcnt before barrier -> LDS ready
#pragma unroll
    for (int kk = 0; kk < 64; kk += 32) {
      bfrag af[4], bf[4];
#pragma unroll
      for (int i = 0; i < 4; ++i)
        af[i] = *reinterpret_cast<const bfrag*>(&As[(wr * 64 + i * 16 + q) * 64 + kk + g * 8]);
#pragma unroll
      for (int j = 0; j < 4; ++j)
        bf[j] = *reinterpret_cast<const bfrag*>(&Bs[(wc * 64 + j * 16 + q) * 64 + kk + g * 8]);
#pragma unroll
      for (int i = 0; i < 4; ++i)
#pragma unroll
        for (int j = 0; j < 4; ++j)
          acc[i][j] = __builtin_amdgcn_mfma_f32_16x16x32_bf16(af[i], bf[j], acc[i][j], 0, 0, 0);
    }
  }

  float bv[4];
#pragma unroll
  for (int j = 0; j < 4; ++j) bv[j] = bias[n0 + wc * 64 + j * 16 + q];
#pragma unroll
  for (int i = 0; i < 4; ++i)
#pragma unroll
    for (int j = 0; j < 4; ++j)
#pragma unroll
      for (int r = 0; r < 4; ++r) {
        int row = m0 + wr * 64 + i * 16 + g * 4 + r;   // C layout: row=(lane>>4)*4+reg
        int col = n0 + wc * 64 + j * 16 + q;           //           col=lane&15
        float val = acc[i][j][r] + bv[j];
        if (OUTF32)
          ((float*)Cout)[(size_t)row * N + col] = val;
        else
          ((unsigned short*)Cout)[(size_t)row * N + col] = f2bf(val);
      }
}

// ---------------- flash attention ----------------
// block = (qtile, h, b); 256 threads = 4 waves, each wave owns 16 q-rows. KV tile = 64.
// Swapped QK^T: mfma(K, Q) -> lane holds 16 scores for q = lane&15 (kv = f*16 + g*4 + r).
__global__ __launch_bounds__(256, 2) void attn_kernel(const unsigned short* __restrict__ Qp,
                                                      const unsigned short* __restrict__ Kp,
                                                      const unsigned short* __restrict__ Vp,
                                                      const unsigned long long* __restrict__ mbits,
                                                      unsigned short* __restrict__ ctx) {
  __shared__ unsigned short Ks[64 * 64];   // [kv][dk]
  __shared__ unsigned short Vt[64 * 64];   // transposed: [dk][kv]
  __shared__ unsigned short Ps[4][16 * 64];  // per-wave P tile [q][kv]

  const int t = threadIdx.x, lane = t & 63, wave = t >> 6;
  const int g = lane >> 4, q = lane & 15;
  const int qt = blockIdx.x, h = blockIdx.y, b = blockIdx.z;
  const int q0 = qt * 64;
  const int qrow = q0 + wave * 16 + q;  // this lane's q row (for frags / mask)

  const size_t qoff = ((size_t)b * S_ + qrow) * D_ + h * 64;
  bfrag qf0 = *reinterpret_cast<const bfrag*>(&Qp[qoff + g * 8]);
  bfrag qf1 = *reinterpret_cast<const bfrag*>(&Qp[qoff + 32 + g * 8]);

  float m_run = -INFINITY, l_run = 0.f;
  f32x4 acc_o[4] = {};  // [d-frag]; C layout rows = q' = g*4+reg, cols = d = nf*16 + q

  const int vpair = (t >> 3) * 2;       // V staging: 2 kv rows per thread
  const int vcol0 = (t & 7) * 8;        // 8 d values

  for (int kv0 = 0; kv0 < S_; kv0 += 64) {
    __syncthreads();
    // stage K tile via global_load_lds (linear [kv][dk])
#pragma unroll
    for (int c = 0; c < 2; ++c)
      async_copy16((char*)Ks + c * 4096 + wave * 1024,
                   &Kp[((size_t)b * S_ + kv0 + c * 32 + (t >> 3)) * D_ + h * 64 + (t & 7) * 8]);
    // stage V transposed (reg round-trip; pairs kv rows so writes are b32)
    u16x8 v0 = *reinterpret_cast<const u16x8*>(&Vp[((size_t)b * S_ + kv0 + vpair) * D_ + h * 64 + vcol0]);
    u16x8 v1 = *reinterpret_cast<const u16x8*>(&Vp[((size_t)b * S_ + kv0 + vpair + 1) * D_ + h * 64 + vcol0]);
#pragma unroll
    for (int i = 0; i < 8; ++i) {
      u16x2 pr; pr[0] = v0[i]; pr[1] = v1[i];
      *reinterpret_cast<u16x2*>(&Vt[(vcol0 + i) * 64 + vpair]) = pr;
    }
    __syncthreads();

    // QK^T (swapped): sc[f] is C[kv][q] for kv-frag f
    f32x4 sc[4] = {};
#pragma unroll
    for (int f = 0; f < 4; ++f) {
      bfrag kf0 = *reinterpret_cast<const bfrag*>(&Ks[(f * 16 + q) * 64 + g * 8]);
      bfrag kf1 = *reinterpret_cast<const bfrag*>(&Ks[(f * 16 + q) * 64 + 32 + g * 8]);
      sc[f] = __builtin_amdgcn_mfma_f32_16x16x32_bf16(kf0, qf0, sc[f], 0, 0, 0);
      sc[f] = __builtin_amdgcn_mfma_f32_16x16x32_bf16(kf1, qf1, sc[f], 0, 0, 0);
    }

    // mask + online softmax (lane owns q = lane&15, 16 kv values)
    unsigned long long mw = mbits[((size_t)b * S_ + qrow) * (S_ / 64) + (kv0 >> 6)];
    float s[16];
    float tmax = -INFINITY;
#pragma unroll
    for (int f = 0; f < 4; ++f)
#pragma unroll
      for (int r = 0; r < 4; ++r) {
        int kvl = f * 16 + g * 4 + r;
        float v = sc[f][r] * 0.125f;                 // 1/sqrt(DK)
        if (!((mw >> kvl) & 1ull)) v = -1e9f;        // matches reference mask semantics
        s[f * 4 + r] = v;
        tmax = fmaxf(tmax, v);
      }
    tmax = fmaxf(tmax, __shfl_xor(tmax, 16));
    tmax = fmaxf(tmax, __shfl_xor(tmax, 32));
    float mnew = fmaxf(m_run, tmax);
    float corr = __expf(m_run - mnew);  // -inf first iter -> 0, no NaN (mnew finite)
    float tsum = 0.f;
#pragma unroll
    for (int f = 0; f < 4; ++f) {
      u16x4 pw;
#pragma unroll
      for (int r = 0; r < 4; ++r) {
        float p = __expf(s[f * 4 + r] - mnew);
        tsum += p;
        pw[r] = f2bf(p);
      }
      *reinterpret_cast<u16x4*>(&Ps[wave][q * 64 + f * 16 + g * 4]) = pw;  // P[q][kv]
    }
    tsum += __shfl_xor(tsum, 16);
    tsum += __shfl_xor(tsum, 32);
    l_run = l_run * corr + tsum;
    m_run = mnew;

    // rescale accumulator (acc_o rows are q' = g*4+j; corr lives at lane q'==lane&15)
#pragma unroll
    for (int j = 0; j < 4; ++j) {
      float cj = __shfl(corr, g * 4 + j);
#pragma unroll
      for (int nf = 0; nf < 4; ++nf) acc_o[nf][j] *= cj;
    }

    // PV: mfma(P, V) ; P from per-wave LDS tile, V from transposed tile
#pragma unroll
    for (int kk = 0; kk < 64; kk += 32) {
      bfrag pf = *reinterpret_cast<const bfrag*>(&Ps[wave][q * 64 + kk + g * 8]);
#pragma unroll
      for (int nf = 0; nf < 4; ++nf) {
        bfrag vf = *reinterpret_cast<const bfrag*>(&Vt[(nf * 16 + q) * 64 + kk + g * 8]);
        acc_o[nf] = __builtin_amdgcn_mfma_f32_16x16x32_bf16(pf, vf, acc_o[nf], 0, 0, 0);
      }
    }
  }

  // epilogue: divide by l, write ctx[b, s, h*64 + d] (== [B,S,D] after head merge)
#pragma unroll
  for (int j = 0; j < 4; ++j) {
    float lj = __shfl(l_run, g * 4 + j);
    float inv = 1.f / lj;
#pragma unroll
    for (int nf = 0; nf < 4; ++nf) {
      int row = q0 + wave * 16 + g * 4 + j;
      int col = h * 64 + nf * 16 + q;
      ctx[((size_t)b * S_ + row) * D_ + col] = f2bf(acc_o[nf][j] * inv);
    }
  }
}

// ---------------- launch ----------------
extern "C" void kernel_launch(void* const* d_in, const int* in_sizes, int n_in,
                              void* d_out, int out_size, void* d_ws, size_t ws_size,
                              hipStream_t stream) {
  const float* q = (const float*)d_in[0];
  const float* k = (const float*)d_in[1];
  const float* v = (const float*)d_in[2];
  const int* mask = (const int*)d_in[3];
  const float* w_q = (const float*)d_in[4];
  const float* b_q = (const float*)d_in[5];
  const float* w_k = (const float*)d_in[6];
  const float* b_k = (const float*)d_in[7];
  const float* w_v = (const float*)d_in[8];
  const float* b_v = (const float*)d_in[9];
  const float* w_o = (const float*)d_in[10];
  const float* b_o = (const float*)d_in[11];
  float* out = (float*)d_out;

  char* ws = (char*)d_ws;
  const size_t SZ_IN = (size_t)MROWS * D_ * 2;   // 8 MB bf16 [4096][1024]
  const size_t SZ_W = (size_t)D_ * D_ * 2;       // 2 MB bf16 [1024][1024]
  unsigned short* qb = (unsigned short*)(ws + 0);
  unsigned short* kb = (unsigned short*)(ws + SZ_IN);
  unsigned short* vb = (unsigned short*)(ws + 2 * SZ_IN);
  unsigned short* wqb = (unsigned short*)(ws + 3 * SZ_IN);
  unsigned short* wkb = (unsigned short*)(ws + 3 * SZ_IN + SZ_W);
  unsigned short* wvb = (unsigned short*)(ws + 3 * SZ_IN + 2 * SZ_W);
  unsigned short* wob = (unsigned short*)(ws + 3 * SZ_IN + 3 * SZ_W);
  unsigned short* Qp = (unsigned short*)(ws + 3 * SZ_IN + 4 * SZ_W);
  unsigned short* Kp = (unsigned short*)(ws + 4 * SZ_IN + 4 * SZ_W);
  unsigned short* Vp = (unsigned short*)(ws + 5 * SZ_IN + 4 * SZ_W);
  unsigned short* ctx = (unsigned short*)(ws + 6 * SZ_IN + 4 * SZ_W);
  unsigned long long* mbits = (unsigned long long*)(ws + 7 * SZ_IN + 4 * SZ_W);

  // 1) convert inputs + weights to bf16
  cvt_bf16<<<4096, 256, 0, stream>>>(q, qb, MROWS * D_ / 4);
  cvt_bf16<<<4096, 256, 0, stream>>>(k, kb, MROWS * D_ / 4);
  cvt_bf16<<<4096, 256, 0, stream>>>(v, vb, MROWS * D_ / 4);
  cvt_bf16<<<1024, 256, 0, stream>>>(w_q, wqb, D_ * D_ / 4);
  cvt_bf16<<<1024, 256, 0, stream>>>(w_k, wkb, D_ * D_ / 4);
  cvt_bf16<<<1024, 256, 0, stream>>>(w_v, wvb, D_ * D_ / 4);
  cvt_bf16<<<1024, 256, 0, stream>>>(w_o, wob, D_ * D_ / 4);

  // 2) pack mask bits (2*2048*2048 elems)
  pack_mask<<<32768, 256, 0, stream>>>(mask, mbits);

  // 3) QKV projections (bf16 out)
  dim3 gg(D_ / 128, MROWS / 128);
  gemm_bt<false><<<gg, 256, 0, stream>>>(qb, wqb, b_q, Qp, MROWS, D_, D_);
  gemm_bt<false><<<gg, 256, 0, stream>>>(kb, wkb, b_k, Kp, MROWS, D_, D_);
  gemm_bt<false><<<gg, 256, 0, stream>>>(vb, wvb, b_v, Vp, MROWS, D_, D_);

  // 4) attention (qtile fastest in x so blocks sharing (b,h) K/V are dispatched together)
  attn_kernel<<<dim3(S_ / 64, 16, 2), 256, 0, stream>>>(Qp, Kp, Vp, mbits, ctx);

  // 5) output projection (fp32 out + bias) straight to d_out
  gemm_bt<true><<<gg, 256, 0, stream>>>(ctx, wob, b_o, out, MROWS, D_, D_);
}

// Round 3
// 174.680 us; speedup vs baseline: 1.8096x; 1.8096x over previous
//
#include <hip/hip_runtime.h>
#include <hip/hip_bf16.h>
#include <cstdint>

#define DEVINL __device__ __forceinline__

using bfrag = __attribute__((ext_vector_type(8))) __bf16;     // MFMA A/B operand (4 VGPRs)
using f32x4 = __attribute__((ext_vector_type(4))) float;      // MFMA C/D
using u16x2 = __attribute__((ext_vector_type(2))) unsigned short;
using u16x4 = __attribute__((ext_vector_type(4))) unsigned short;
using u16x8 = __attribute__((ext_vector_type(8))) unsigned short;

// Problem constants (B=2, S=2048, D=1024, H=16, DK=64)
static constexpr int S_ = 2048;
static constexpr int D_ = 1024;
static constexpr int MROWS = 4096;  // B*S

DEVINL unsigned short f2bf(float f) {  // RNE f32 -> bf16 (compiler emits v_cvt, pairs to cvt_pk)
  __hip_bfloat16 h = __float2bfloat16(f);
  union { __hip_bfloat16 h; unsigned short u; } cv; cv.h = h; return cv.u;
}

DEVINL void async_copy16(void* lds, const void* g) {
  // HW adds lane*16 to the (wave-uniform) LDS base
  __builtin_amdgcn_global_load_lds(
      (const __attribute__((address_space(1))) unsigned int*)g,
      (__attribute__((address_space(3))) unsigned int*)lds, 16, 0, 0);
}

// ---------------- fused fp32 -> bf16 convert for all 7 tensors ----------------
struct CvtAll {
  const float* src[7];
  unsigned short* dst[7];
  int n4[7];
};

__global__ __launch_bounds__(256) void cvt_all(CvtAll a) {
  const float* __restrict__ in = a.src[blockIdx.y];
  unsigned short* __restrict__ out = a.dst[blockIdx.y];
  const int n4 = a.n4[blockIdx.y];
  for (int i = blockIdx.x * 256 + threadIdx.x; i < n4; i += gridDim.x * 256) {
    f32x4 v = ((const f32x4*)in)[i];
    u16x4 o;
    o[0] = f2bf(v[0]); o[1] = f2bf(v[1]); o[2] = f2bf(v[2]); o[3] = f2bf(v[3]);
    ((u16x4*)out)[i] = o;
  }
}

// ---------------- mask [B,1,S,S] int32 -> bitmask (64 kv per u64 word) ----------------
__global__ __launch_bounds__(256) void pack_mask(const int* __restrict__ mask,
                                                 unsigned long long* __restrict__ bits) {
  size_t i = (size_t)blockIdx.x * 256 + threadIdx.x;
  unsigned long long b = __ballot(mask[i] != 0);
  if ((threadIdx.x & 63) == 0) bits[i >> 6] = b;
}

// ---------------- GEMM body: C[m,n] = oscale*(bias[n] + sum_k A[m,k]*W[n,k]) ----------------
// 128x128 tile, BK=64, 256 threads (4 waves, 64x64 quadrant each), 16x16x32 bf16 MFMA.
// 2-phase structure: T2 swizzle is measured-null here (regime gate), so LDS stays linear.
template <bool OUTF32>
DEVINL void gemm_body(const unsigned short* __restrict__ A, const unsigned short* __restrict__ W,
                      const float* __restrict__ bias, void* __restrict__ Cout,
                      int K, int N, float oscale,
                      unsigned short* As, unsigned short* Bs, int m0, int n0) {
  const int t = threadIdx.x;
  const int lane = t & 63, wave = t >> 6;
  const int wr = wave >> 1, wc = wave & 1;
  const int g = lane >> 4, q = lane & 15;

  f32x4 acc[4][4] = {};  // [mi][nj]

  const int srow = t >> 3;
  const int scol = (t & 7) * 8;
  const size_t abase = (size_t)(m0 + srow) * K + scol;
  const size_t bbase = (size_t)(n0 + srow) * K + scol;
  char* AsB = (char*)As;
  char* BsB = (char*)Bs;

  for (int k0 = 0; k0 < K; k0 += 64) {
    __syncthreads();
#pragma unroll
    for (int c = 0; c < 4; ++c) {
      async_copy16(AsB + c * 4096 + wave * 1024, A + abase + (size_t)c * 32 * K + k0);
      async_copy16(BsB + c * 4096 + wave * 1024, W + bbase + (size_t)c * 32 * K + k0);
    }
    __syncthreads();
#pragma unroll
    for (int kk = 0; kk < 64; kk += 32) {
      bfrag af[4], bf[4];
#pragma unroll
      for (int i = 0; i < 4; ++i)
        af[i] = *reinterpret_cast<const bfrag*>(&As[(wr * 64 + i * 16 + q) * 64 + kk + g * 8]);
#pragma unroll
      for (int j = 0; j < 4; ++j)
        bf[j] = *reinterpret_cast<const bfrag*>(&Bs[(wc * 64 + j * 16 + q) * 64 + kk + g * 8]);
      __builtin_amdgcn_s_setprio(1);
#pragma unroll
      for (int i = 0; i < 4; ++i)
#pragma unroll
        for (int j = 0; j < 4; ++j)
          acc[i][j] = __builtin_amdgcn_mfma_f32_16x16x32_bf16(af[i], bf[j], acc[i][j], 0, 0, 0);
      __builtin_amdgcn_s_setprio(0);
    }
  }

  float bv[4];
#pragma unroll
  for (int j = 0; j < 4; ++j) bv[j] = bias[n0 + wc * 64 + j * 16 + q];
#pragma unroll
  for (int i = 0; i < 4; ++i)
#pragma unroll
    for (int j = 0; j < 4; ++j)
#pragma unroll
      for (int r = 0; r < 4; ++r) {
        int row = m0 + wr * 64 + i * 16 + g * 4 + r;   // C layout: row=(lane>>4)*4+reg
        int col = n0 + wc * 64 + j * 16 + q;           //           col=lane&15
        float val = (acc[i][j][r] + bv[j]) * oscale;
        if (OUTF32)
          ((float*)Cout)[(size_t)row * N + col] = val;
        else
          ((unsigned short*)Cout)[(size_t)row * N + col] = f2bf(val);
      }
}

// QKV projections fused via z; Q output pre-scaled by 1/sqrt(DK)=0.125 (free in epilogue).
__global__ __launch_bounds__(256, 2) void qkv_gemm(const unsigned short* __restrict__ Abase,
                                                   const unsigned short* __restrict__ Wbase,
                                                   const float* __restrict__ b_q,
                                                   const float* __restrict__ b_k,
                                                   const float* __restrict__ b_v,
                                                   unsigned short* __restrict__ Obase) {
  __shared__ unsigned short As[128 * 64];
  __shared__ unsigned short Bs[128 * 64];
  const int z = blockIdx.z;
  const unsigned short* A = Abase + (size_t)z * MROWS * D_;
  const unsigned short* W = Wbase + (size_t)z * D_ * D_;
  const float* bias = (z == 0) ? b_q : (z == 1) ? b_k : b_v;
  unsigned short* out = Obase + (size_t)z * MROWS * D_;
  const float oscale = (z == 0) ? 0.125f : 1.0f;
  gemm_body<false>(A, W, bias, out, D_, D_, oscale, As, Bs, blockIdx.y * 128, blockIdx.x * 128);
}

__global__ __launch_bounds__(256, 2) void out_gemm(const unsigned short* __restrict__ A,
                                                   const unsigned short* __restrict__ W,
                                                   const float* __restrict__ bias,
                                                   float* __restrict__ out) {
  __shared__ unsigned short As[128 * 64];
  __shared__ unsigned short Bs[128 * 64];
  gemm_body<true>(A, W, bias, out, D_, D_, 1.0f, As, Bs, blockIdx.y * 128, blockIdx.x * 128);
}

// ---------------- flash attention ----------------
// block = (qtile, h, b); 256 threads = 4 waves, each wave owns 16 q rows. KV tile = 64.
// Swapped QK^T: mfma(K, Q) -> lane holds 16 scores for q = lane&15.
// All LDS tiles XOR-swizzled on the 16B granule (T2); K staged via global_load_lds with
// pre-swizzled SOURCE (linear dest, rule 21); V reg-staged transposed with swizzled writes.
// Pipeline: V[t+1] global->reg issued before QK^T; K[t+1] async issued after barrier-2
// so it streams during PV (T14). Defer-max rescale (T13). setprio around MFMA (T5).
__global__ __launch_bounds__(256, 2) void attn_kernel(const unsigned short* __restrict__ Qp,
                                                      const unsigned short* __restrict__ Kp,
                                                      const unsigned short* __restrict__ Vp,
                                                      const unsigned long long* __restrict__ mbits,
                                                      unsigned short* __restrict__ ctx) {
  __shared__ unsigned short Ks[64 * 64];     // logical [kv][dk], granule ^= (kv&7)
  __shared__ unsigned short Vt[64 * 64];     // logical [dk][kv], granule ^= (d&7)^((d>>3)&7)
  __shared__ unsigned short Ps[4][16 * 64];  // per-wave [q][kv], granule ^= (q&7)

  const int t = threadIdx.x, lane = t & 63, wave = t >> 6;
  const int g = lane >> 4, q = lane & 15;
  const int qt = blockIdx.x, h = blockIdx.y, b = blockIdx.z;
  const int q0 = qt * 64;
  const int qrow = q0 + wave * 16 + q;

  // Q frags (already scaled by 0.125 in projection)
  const size_t qoff = ((size_t)b * S_ + qrow) * D_ + h * 64;
  bfrag qf0 = *reinterpret_cast<const bfrag*>(&Qp[qoff + g * 8]);
  bfrag qf1 = *reinterpret_cast<const bfrag*>(&Qp[qoff + 32 + g * 8]);

  float m_run = -INFINITY, l_run = 0.f;
  f32x4 acc_o[4] = {};  // [d-frag]; rows q'=g*4+reg, cols d=nf*16+q

  // K staging: LDS linear row r = c*32 + wave*8 + (lane>>3) => r&7 = lane>>3;
  // physical granule slot = lane&7 => logical col granule = (lane&7)^(lane>>3).
  const int ksr = wave * 8 + (lane >> 3);
  const int ksc = ((lane & 7) ^ (lane >> 3)) * 8;
  const size_t kvbase = (size_t)b * S_ * D_ + (size_t)h * 64;

  // V reg-staging: 2 kv rows x 8 d per thread
  const int vpair = (t >> 3) * 2;
  const int vcol0 = (t & 7) * 8;

  char* KsB = (char*)Ks;
  char* VtB = (char*)Vt;
  char* PsB = (char*)&Ps[wave][0];

  // prologue: K[0] async, V[0] regs, mask[0]
#pragma unroll
  for (int c = 0; c < 2; ++c)
    async_copy16(KsB + c * 4096 + wave * 1024, &Kp[kvbase + (size_t)(c * 32 + ksr) * D_ + ksc]);
  u16x8 va = *reinterpret_cast<const u16x8*>(&Vp[kvbase + (size_t)vpair * D_ + vcol0]);
  u16x8 vb = *reinterpret_cast<const u16x8*>(&Vp[kvbase + (size_t)(vpair + 1) * D_ + vcol0]);
  const unsigned long long* mrow = &mbits[((size_t)b * S_ + qrow) * (S_ / 64)];
  unsigned long long mw = mrow[0];

  constexpr int NT = S_ / 64;
  for (int ti = 0; ti < NT; ++ti) {
    const int kvn = (ti + 1) * 64;
    __syncthreads();  // B1: K[ti] landed (vmcnt drain), prev PV done

    // write V[ti] regs -> Vt, swizzled: s(d) = i ^ (t&7) for d = vcol0+i
#pragma unroll
    for (int i = 0; i < 8; ++i) {
      u16x2 pr; pr[0] = va[i]; pr[1] = vb[i];
      *reinterpret_cast<u16x2*>(VtB + (vcol0 + i) * 128 +
                                ((((vpair >> 3) ^ i ^ (t & 7)) & 7) << 4) + (vpair & 7) * 2) = pr;
    }
    // prefetch V[ti+1] + mask[ti+1] (latency hides under QK^T + softmax + PV)
    unsigned long long mw_n = 0;
    if (ti + 1 < NT) {
      va = *reinterpret_cast<const u16x8*>(&Vp[kvbase + (size_t)(kvn + vpair) * D_ + vcol0]);
      vb = *reinterpret_cast<const u16x8*>(&Vp[kvbase + (size_t)(kvn + vpair + 1) * D_ + vcol0]);
      mw_n = mrow[ti + 1];
    }

    // QK^T (swapped): sc[f] = C[kv][q] for kv-frag f; Ks row rr=f*16+q, swz ^(q&7)
    f32x4 sc[4];
    __builtin_amdgcn_s_setprio(1);
#pragma unroll
    for (int f = 0; f < 4; ++f) {
      bfrag kf0 = *reinterpret_cast<const bfrag*>(KsB + (f * 16 + q) * 128 + (((0 + g) ^ (q & 7)) << 4));
      bfrag kf1 = *reinterpret_cast<const bfrag*>(KsB + (f * 16 + q) * 128 + (((4 + g) ^ (q & 7)) << 4));
      f32x4 z = {0.f, 0.f, 0.f, 0.f};
      sc[f] = __builtin_amdgcn_mfma_f32_16x16x32_bf16(kf0, qf0, z, 0, 0, 0);
      sc[f] = __builtin_amdgcn_mfma_f32_16x16x32_bf16(kf1, qf1, sc[f], 0, 0, 0);
    }
    __builtin_amdgcn_s_setprio(0);

    // mask + online softmax (lane owns q-row, 16 kv values)
    float s[16];
    float tmax = -INFINITY;
#pragma unroll
    for (int f = 0; f < 4; ++f)
#pragma unroll
      for (int r = 0; r < 4; ++r) {
        int kvl = f * 16 + g * 4 + r;
        float v = sc[f][r];
        if (!((mw >> kvl) & 1ull)) v = -1e9f;
        s[f * 4 + r] = v;
        tmax = fmaxf(tmax, v);
      }
    tmax = fmaxf(tmax, __shfl_xor(tmax, 16));
    tmax = fmaxf(tmax, __shfl_xor(tmax, 32));
    // defer-max (T13): skip rescale unless the row max grew by >8
    if (!__all(tmax <= m_run + 8.f)) {
      float mnew = fmaxf(m_run, tmax);
      float corr = __expf(m_run - mnew);  // -inf path -> 0, no NaN
      l_run *= corr;
#pragma unroll
      for (int j = 0; j < 4; ++j) {
        float cj = __shfl(corr, g * 4 + j);
#pragma unroll
        for (int nf = 0; nf < 4; ++nf) acc_o[nf][j] *= cj;
      }
      m_run = mnew;
    }
    float tsum = 0.f;
#pragma unroll
    for (int f = 0; f < 4; ++f) {
      u16x4 pw;
#pragma unroll
      for (int r = 0; r < 4; ++r) {
        float p = __expf(s[f * 4 + r] - m_run);  // bounded by e^8 under defer
        tsum += p;
        pw[r] = f2bf(p);
      }
      // P[q][f*16+g*4 ..+3]: granule f*2+(g>>1) ^ (q&7), byte offset (g&1)*8
      *reinterpret_cast<u16x4*>(PsB + q * 128 + (((f * 2 + (g >> 1)) ^ (q & 7)) << 4) + (g & 1) * 8) = pw;
    }
    tsum += __shfl_xor(tsum, 16);
    tsum += __shfl_xor(tsum, 32);
    l_run += tsum;

    __syncthreads();  // B2: Ps+Vt visible; all Ks reads done
    // issue K[ti+1] async now -> streams into LDS during PV
    if (ti + 1 < NT) {
#pragma unroll
      for (int c = 0; c < 2; ++c)
        async_copy16(KsB + c * 4096 + wave * 1024,
                     &Kp[kvbase + (size_t)(kvn + c * 32 + ksr) * D_ + ksc]);
    }

    // PV: mfma(P, V); kk8 = kv-granule base (kk/8), kk in {0,32}
    __builtin_amdgcn_s_setprio(1);
#pragma unroll
    for (int kk8 = 0; kk8 < 8; kk8 += 4) {
      bfrag pf = *reinterpret_cast<const bfrag*>(PsB + q * 128 + (((kk8 + g) ^ (q & 7)) << 4));
#pragma unroll
      for (int nf = 0; nf < 4; ++nf) {
        int d = nf * 16 + q;
        int sd = (q & 7) ^ ((2 * nf + (q >> 3)) & 7);
        bfrag vf = *reinterpret_cast<const bfrag*>(VtB + d * 128 + (((kk8 + g) ^ sd) << 4));
        acc_o[nf] = __builtin_amdgcn_mfma_f32_16x16x32_bf16(pf, vf, acc_o[nf], 0, 0, 0);
      }
    }
    __builtin_amdgcn_s_setprio(0);
    mw = mw_n;
  }

  // epilogue: divide by l, write ctx[b, s, h*64 + d]
#pragma unroll
  for (int j = 0; j < 4; ++j) {
    float lj = __shfl(l_run, g * 4 + j);
    float inv = 1.f / lj;
#pragma unroll
    for (int nf = 0; nf < 4; ++nf) {
      int row = q0 + wave * 16 + g * 4 + j;
      int col = h * 64 + nf * 16 + q;
      ctx[((size_t)b * S_ + row) * D_ + col] = f2bf(acc_o[nf][j] * inv);
    }
  }
}

// ---------------- launch ----------------
extern "C" void kernel_launch(void* const* d_in, const int* in_sizes, int n_in,
                              void* d_out, int out_size, void* d_ws, size_t ws_size,
                              hipStream_t stream) {
  const float* q = (const float*)d_in[0];
  const float* k = (const float*)d_in[1];
  const float* v = (const float*)d_in[2];
  const int* mask = (const int*)d_in[3];
  const float* w_q = (const float*)d_in[4];
  const float* b_q = (const float*)d_in[5];
  const float* w_k = (const float*)d_in[6];
  const float* b_k = (const float*)d_in[7];
  const float* w_v = (const float*)d_in[8];
  const float* b_v = (const float*)d_in[9];
  const float* w_o = (const float*)d_in[10];
  const float* b_o = (const float*)d_in[11];
  float* out = (float*)d_out;

  char* ws = (char*)d_ws;
  const size_t SZ_IN = (size_t)MROWS * D_ * 2;   // 8 MB bf16 [4096][1024]
  const size_t SZ_W = (size_t)D_ * D_ * 2;       // 2 MB bf16 [1024][1024]
  unsigned short* qb = (unsigned short*)(ws + 0);           // qb,kb,vb contiguous
  unsigned short* wqb = (unsigned short*)(ws + 3 * SZ_IN);  // wq,wk,wv contiguous
  unsigned short* wob = (unsigned short*)(ws + 3 * SZ_IN + 3 * SZ_W);
  unsigned short* Qp = (unsigned short*)(ws + 3 * SZ_IN + 4 * SZ_W);  // Qp,Kp,Vp contiguous
  unsigned short* ctx = (unsigned short*)(ws + 6 * SZ_IN + 4 * SZ_W);
  unsigned long long* mbits = (unsigned long long*)(ws + 7 * SZ_IN + 4 * SZ_W);
  unsigned short* kb = qb + MROWS * D_;
  unsigned short* vb = kb + MROWS * D_;
  unsigned short* wkb = wqb + D_ * D_;
  unsigned short* wvb = wkb + D_ * D_;
  unsigned short* Kp = Qp + MROWS * D_;
  unsigned short* Vp = Kp + MROWS * D_;

  // 1) convert all inputs + weights to bf16 (single fused launch)
  CvtAll ca;
  ca.src[0] = q;   ca.dst[0] = qb;  ca.n4[0] = MROWS * D_ / 4;
  ca.src[1] = k;   ca.dst[1] = kb;  ca.n4[1] = MROWS * D_ / 4;
  ca.src[2] = v;   ca.dst[2] = vb;  ca.n4[2] = MROWS * D_ / 4;
  ca.src[3] = w_q; ca.dst[3] = wqb; ca.n4[3] = D_ * D_ / 4;
  ca.src[4] = w_k; ca.dst[4] = wkb; ca.n4[4] = D_ * D_ / 4;
  ca.src[5] = w_v; ca.dst[5] = wvb; ca.n4[5] = D_ * D_ / 4;
  ca.src[6] = w_o; ca.dst[6] = wob; ca.n4[6] = D_ * D_ / 4;
  cvt_all<<<dim3(1024, 7), 256, 0, stream>>>(ca);

  // 2) pack mask bits (2*2048*2048 elems)
  pack_mask<<<32768, 256, 0, stream>>>(mask, mbits);

  // 3) QKV projections (bf16 out; Q pre-scaled by 0.125)
  qkv_gemm<<<dim3(D_ / 128, MROWS / 128, 3), 256, 0, stream>>>(qb, wqb, b_q, b_k, b_v, Qp);

  // 4) attention
  attn_kernel<<<dim3(S_ / 64, 16, 2), 256, 0, stream>>>(Qp, Kp, Vp, mbits, ctx);

  // 5) output projection (fp32 + bias) straight to d_out
  out_gemm<<<dim3(D_ / 128, MROWS / 128), 256, 0, stream>>>(ctx, wob, b_o, out);
}